// Round 5
// baseline (160.494 us; speedup 1.0000x reference)
//
#include <hip/hip_runtime.h>

// Problem constants (from reference setup_inputs).
#define BATCH  4
#define NQ     8192
#define NA     6890
#define NSPLIT 16              // anchor splits = waves per block
#define QPB    64              // queries per block = one wave width
#define GPW    54              // 8-anchor groups per wave
#define NAPAD  (NSPLIT*GPW*8)  // 6912 padded anchors
#define PADH   1.0e30f

// ---- precompute: packed[b][k] = (x, y, z, 0.5*|a|^2), padded; also zero out/zbuf ----
__global__ void precompute_kernel(const float* __restrict__ anchor,
                                  float4* __restrict__ packed,
                                  int* __restrict__ zbuf,
                                  float* __restrict__ out) {
    const int i = blockIdx.x * blockDim.x + threadIdx.x;
    if (i < BATCH) out[i] = 0.0f;      // d_out is poisoned 0xAA each call
    if (i == 0) zbuf[0] = 0;           // runtime zero (divergence decoy)
    if (i >= BATCH * NAPAD) return;
    const int b = i / NAPAD, k = i - b * NAPAD;
    float4 o;
    if (k < NA) {
        const float* a = anchor + ((size_t)b * NA + k) * 3;
        const float x = a[0], y = a[1], z = a[2];
        o = make_float4(x, y, z, 0.5f * (x*x + y*y + z*z));
    } else {
        o = make_float4(0.f, 0.f, 0.f, PADH);
    }
    packed[i] = o;
}

// score = 0.5|a|^2 - q.a  (monotone in d^2 per query).
// 3 VALU ops: fma chain with free negate modifiers.
#define SCORE(ax,ay,az,hh,dst) \
  dst = fmaf(-(az), qz, fmaf(-(ay), qy, fmaf(-(ax), qx, (hh))))

__global__ __launch_bounds__(NSPLIT * 64, 4)
void collision_kernel(const float* __restrict__ query,
                      const float* __restrict__ anchor,
                      const float* __restrict__ normals,
                      const float4* __restrict__ packed,
                      const int* __restrict__ zbuf,
                      float* __restrict__ out) {
    __shared__ float s_sc[NSPLIT][QPB];
    __shared__ int   s_gd[NSPLIT][QPB];

    const int lane = threadIdx.x & 63;
    const int wave = threadIdx.x >> 6;
    const int blocksPerBatch = NQ / QPB;                  // 128
    const int b = blockIdx.x / blocksPerBatch;
    const int q = (blockIdx.x % blocksPerBatch) * QPB + lane;

    const float* qp = query + ((size_t)b * NQ + q) * 3;
    const float qx = qp[0], qy = qp[1], qz = qp[2];

    const float4* __restrict__ PK = packed + (size_t)b * NAPAD;
    // Divergence decoy: zero==0 at runtime, but (zero & lane) is divergent to
    // the compiler -> anchor loads become VMEM (global_load_dwordx4, in-order
    // vmcnt, deep pipelining) instead of SMEM (out-of-order, lgkmcnt(0)-only).
    const int zero = zbuf[0];
    const float4* __restrict__ P4 = PK + (size_t)wave * GPW * 8 + (zero & lane);
    const int gbase = wave * GPW;

    float best = PADH;   // pad sentinel can never strictly win
    int   bgid = gbase;

    #pragma unroll 2
    for (int g = 0; g < GPW; ++g) {
        const float4 a0 = P4[8*g+0];
        const float4 a1 = P4[8*g+1];
        const float4 a2 = P4[8*g+2];
        const float4 a3 = P4[8*g+3];
        const float4 a4 = P4[8*g+4];
        const float4 a5 = P4[8*g+5];
        const float4 a6 = P4[8*g+6];
        const float4 a7 = P4[8*g+7];
        float s0,s1,s2,s3,s4,s5,s6,s7;
        SCORE(a0.x,a0.y,a0.z,a0.w,s0);
        SCORE(a1.x,a1.y,a1.z,a1.w,s1);
        SCORE(a2.x,a2.y,a2.z,a2.w,s2);
        SCORE(a3.x,a3.y,a3.z,a3.w,s3);
        SCORE(a4.x,a4.y,a4.z,a4.w,s4);
        SCORE(a5.x,a5.y,a5.z,a5.w,s5);
        SCORE(a6.x,a6.y,a6.z,a6.w,s6);
        SCORE(a7.x,a7.y,a7.z,a7.w,s7);
        const float mA = fminf(fminf(s0,s1),s2);   // v_min3
        const float mB = fminf(fminf(s3,s4),s5);
        const float mC = fminf(fminf(s6,s7),mA);
        const float mg = fminf(mB,mC);
        const bool p = (mg < best);                // strict <: earliest group wins
        best = p ? mg : best;
        bgid = p ? (gbase + g) : bgid;
    }

    s_sc[wave][lane] = best;
    s_gd[wave][lane] = bgid;
    __syncthreads();

    if (threadIdx.x < QPB) {
        float bs = s_sc[0][lane];
        int   bg = s_gd[0][lane];
        #pragma unroll
        for (int s = 1; s < NSPLIT; ++s) {
            const float v = s_sc[s][lane];
            const int  gi = s_gd[s][lane];
            if (v < bs) { bs = v; bg = gi; }   // ascending s: ties keep earliest
        }
        // Rescan winning group (8 anchors) to resolve the exact index.
        // Must use the SAME score expression for bit-identical values.
        const float4* G = PK + (size_t)bg * 8;
        float rb = PADH; int rj = 0;
        #pragma unroll
        for (int j = 0; j < 8; ++j) {
            const float4 a = G[j];
            float sc; SCORE(a.x, a.y, a.z, a.w, sc);
            if (sc < rb) { rb = sc; rj = j; }  // ascending j: first occurrence
        }
        const int bidx = bg * 8 + rj;          // < NA (pads can't win)
        // Exact d2 / dot for the collision predicate.
        const float* ap = anchor + ((size_t)b * NA + bidx) * 3;
        const float* np = normals + ((size_t)b * NA + bidx) * 3;
        const float dx = qx - ap[0], dy = qy - ap[1], dz = qz - ap[2];
        const float d2  = fmaf(dz, dz, fmaf(dy, dy, dx * dx));
        const float dot = fmaf(dz, np[2], fmaf(dy, np[1], dx * np[0]));
        // dot * (l2 <= 0.5) < 0  <=>  dot < 0 && d2 <= 0.25
        const bool coll = (dot < 0.0f) && (d2 <= 0.25f);
        const unsigned long long m = __ballot(coll);
        if (lane == 0) atomicAdd(out + b, (float)__popcll(m));
    }
}

extern "C" void kernel_launch(void* const* d_in, const int* in_sizes, int n_in,
                              void* d_out, int out_size, void* d_ws, size_t ws_size,
                              hipStream_t stream) {
    const float* query   = (const float*)d_in[0];
    const float* anchor  = (const float*)d_in[1];
    const float* normals = (const float*)d_in[2];
    float* out = (float*)d_out;
    float4* packed = (float4*)d_ws;                    // BATCH*NAPAD*16B = 442 KB
    int* zbuf = (int*)(packed + BATCH * NAPAD);        // 4B right after

    const int npre = BATCH * NAPAD;
    precompute_kernel<<<dim3((npre + 255) / 256), dim3(256), 0, stream>>>(
        anchor, packed, zbuf, out);

    const int grid = BATCH * (NQ / QPB);   // 512 blocks x 1024 threads
    collision_kernel<<<dim3(grid), dim3(NSPLIT * 64), 0, stream>>>(
        query, anchor, normals, packed, zbuf, out);
}

// Round 6
// 119.040 us; speedup vs baseline: 1.3482x; 1.3482x over previous
//
#include <hip/hip_runtime.h>

// Problem constants (from reference setup_inputs).
#define BATCH  4
#define NQ     8192
#define NA     6890
#define NSPLIT 16              // anchor chunks = waves per block
#define GPW    54              // 8-anchor groups per wave chunk
#define NAPAD  (NSPLIT*GPW*8)  // 6912 padded anchors
#define PADH   1.0e30f
#define QPB    128             // queries per block (2 per lane)

// ---- precompute: packed[b][k] = (x, y, z, 0.5*|a|^2), padded; zero d_out ----
__global__ void precompute_kernel(const float* __restrict__ anchor,
                                  float4* __restrict__ packed,
                                  float* __restrict__ out) {
    const int i = blockIdx.x * blockDim.x + threadIdx.x;
    if (i < BATCH) out[i] = 0.0f;      // d_out is poisoned 0xAA each call
    if (i >= BATCH * NAPAD) return;
    const int b = i / NAPAD, k = i - b * NAPAD;
    float4 o;
    if (k < NA) {
        const float* a = anchor + ((size_t)b * NA + k) * 3;
        const float x = a[0], y = a[1], z = a[2];
        o = make_float4(x, y, z, 0.5f * (x*x + y*y + z*z));
    } else {
        o = make_float4(0.f, 0.f, 0.f, PADH);
    }
    packed[i] = o;
}

// VALU-pipe broadcast: VGPR(lane j) -> SGPR. The only cheap broadcast on CDNA.
__device__ __forceinline__ float bcast(float v, int j) {
    return __uint_as_float((unsigned)__builtin_amdgcn_readlane((int)__float_as_uint(v), j));
}

// score = 0.5|a|^2 - q.a (monotone in d^2 per query). 4 VALU ops, each with
// <=1 SGPR operand. MUST be the identical expression in main loop and rescan
// so scores are bitwise-equal (first-occurrence tie-break stays exact).
__device__ __forceinline__ float score_fn(float ax, float ay, float az, float hh,
                                          float qx, float qy, float qz) {
    return hh - fmaf(ax, qx, fmaf(ay, qy, az * qz));
}

__global__ __launch_bounds__(NSPLIT * 64, 4)
void collision_kernel(const float* __restrict__ query,
                      const float* __restrict__ anchor,
                      const float* __restrict__ normals,
                      const float4* __restrict__ packed,
                      float* __restrict__ out) {
    __shared__ float s_sc[NSPLIT][QPB];
    __shared__ int   s_gd[NSPLIT][QPB];

    const int lane = threadIdx.x & 63;
    const int wave = threadIdx.x >> 6;
    const int b  = blockIdx.x >> 6;            // batch
    const int qg = blockIdx.x & 63;            // query group (128 queries)
    const int q0 = qg * QPB + lane;            // this lane's two queries
    const int q1 = q0 + 64;

    const float* qp0 = query + ((size_t)b * NQ + q0) * 3;
    const float* qp1 = query + ((size_t)b * NQ + q1) * 3;
    const float qx0 = qp0[0], qy0 = qp0[1], qz0 = qp0[2];
    const float qx1 = qp1[0], qy1 = qp1[1], qz1 = qp1[2];

    const float4* __restrict__ PK = packed + (size_t)b * NAPAD;

    // In-register anchor cache: lane j (j<54) holds the chunk's anchors
    // [8j .. 8j+7] in 8 float4 VGPR quads (one-time coalesced L2-hot load).
    const int src = (lane < GPW) ? lane : (GPW - 1);
    const float4* __restrict__ L = PK + (size_t)wave * GPW * 8 + (size_t)src * 8;
    const float4 a0 = L[0], a1 = L[1], a2 = L[2], a3 = L[3];
    const float4 a4 = L[4], a5 = L[5], a6 = L[6], a7 = L[7];

    const int gbase = wave * GPW;
    float best0 = PADH, best1 = PADH;
    int   bg0 = gbase,  bg1 = gbase;

    #pragma unroll 2
    for (int j = 0; j < GPW; ++j) {
        // Broadcast lane j's 8 anchors (32 readlanes -> SGPRs).
        const float x0=bcast(a0.x,j), y0=bcast(a0.y,j), z0=bcast(a0.z,j), h0=bcast(a0.w,j);
        const float x1=bcast(a1.x,j), y1=bcast(a1.y,j), z1=bcast(a1.z,j), h1=bcast(a1.w,j);
        const float x2=bcast(a2.x,j), y2=bcast(a2.y,j), z2=bcast(a2.z,j), h2=bcast(a2.w,j);
        const float x3=bcast(a3.x,j), y3=bcast(a3.y,j), z3=bcast(a3.z,j), h3=bcast(a3.w,j);
        const float x4=bcast(a4.x,j), y4=bcast(a4.y,j), z4=bcast(a4.z,j), h4=bcast(a4.w,j);
        const float x5=bcast(a5.x,j), y5=bcast(a5.y,j), z5=bcast(a5.z,j), h5=bcast(a5.w,j);
        const float x6=bcast(a6.x,j), y6=bcast(a6.y,j), z6=bcast(a6.z,j), h6=bcast(a6.w,j);
        const float x7=bcast(a7.x,j), y7=bcast(a7.y,j), z7=bcast(a7.z,j), h7=bcast(a7.w,j);
        {   // query 0
            const float s0 = score_fn(x0,y0,z0,h0,qx0,qy0,qz0);
            const float s1 = score_fn(x1,y1,z1,h1,qx0,qy0,qz0);
            const float s2 = score_fn(x2,y2,z2,h2,qx0,qy0,qz0);
            const float s3 = score_fn(x3,y3,z3,h3,qx0,qy0,qz0);
            const float s4 = score_fn(x4,y4,z4,h4,qx0,qy0,qz0);
            const float s5 = score_fn(x5,y5,z5,h5,qx0,qy0,qz0);
            const float s6 = score_fn(x6,y6,z6,h6,qx0,qy0,qz0);
            const float s7 = score_fn(x7,y7,z7,h7,qx0,qy0,qz0);
            const float mA = fminf(fminf(s0,s1),s2);   // v_min3
            const float mB = fminf(fminf(s3,s4),s5);
            const float mC = fminf(fminf(s6,s7),mA);
            const float mg = fminf(mB,mC);
            const bool p = (mg < best0);               // strict <: earliest group
            best0 = p ? mg : best0;
            bg0   = p ? (gbase + j) : bg0;
        }
        {   // query 1
            const float s0 = score_fn(x0,y0,z0,h0,qx1,qy1,qz1);
            const float s1 = score_fn(x1,y1,z1,h1,qx1,qy1,qz1);
            const float s2 = score_fn(x2,y2,z2,h2,qx1,qy1,qz1);
            const float s3 = score_fn(x3,y3,z3,h3,qx1,qy1,qz1);
            const float s4 = score_fn(x4,y4,z4,h4,qx1,qy1,qz1);
            const float s5 = score_fn(x5,y5,z5,h5,qx1,qy1,qz1);
            const float s6 = score_fn(x6,y6,z6,h6,qx1,qy1,qz1);
            const float s7 = score_fn(x7,y7,z7,h7,qx1,qy1,qz1);
            const float mA = fminf(fminf(s0,s1),s2);
            const float mB = fminf(fminf(s3,s4),s5);
            const float mC = fminf(fminf(s6,s7),mA);
            const float mg = fminf(mB,mC);
            const bool p = (mg < best1);
            best1 = p ? mg : best1;
            bg1   = p ? (gbase + j) : bg1;
        }
    }

    s_sc[wave][lane]      = best0;
    s_gd[wave][lane]      = bg0;
    s_sc[wave][64 + lane] = best1;
    s_gd[wave][64 + lane] = bg1;
    __syncthreads();

    if (threadIdx.x < QPB) {   // waves 0 and 1, fully active
        const int col = threadIdx.x;
        float bs = s_sc[0][col];
        int   bg = s_gd[0][col];
        #pragma unroll
        for (int s = 1; s < NSPLIT; ++s) {
            const float v = s_sc[s][col];
            const int  gi = s_gd[s][col];
            if (v < bs) { bs = v; bg = gi; }   // ascending s: ties keep earliest
        }
        // This thread's query coords (col = qidx within block).
        const int qq = qg * QPB + col;
        const float* qp = query + ((size_t)b * NQ + qq) * 3;
        const float qx = qp[0], qy = qp[1], qz = qp[2];
        // Rescan winning group (8 anchors) with the identical score expression.
        const float4* G = PK + (size_t)bg * 8;
        float rb = PADH; int rj = 0;
        #pragma unroll
        for (int j = 0; j < 8; ++j) {
            const float4 a = G[j];
            const float sc = score_fn(a.x, a.y, a.z, a.w, qx, qy, qz);
            if (sc < rb) { rb = sc; rj = j; }  // ascending j: first occurrence
        }
        const int bidx = bg * 8 + rj;          // < NA (pads can't win)
        // Exact d2 / dot for the collision predicate.
        const float* ap = anchor + ((size_t)b * NA + bidx) * 3;
        const float* np = normals + ((size_t)b * NA + bidx) * 3;
        const float dx = qx - ap[0], dy = qy - ap[1], dz = qz - ap[2];
        const float d2  = fmaf(dz, dz, fmaf(dy, dy, dx * dx));
        const float dot = fmaf(dz, np[2], fmaf(dy, np[1], dx * np[0]));
        // dot * (l2 <= 0.5) < 0  <=>  dot < 0 && d2 <= 0.25
        const bool coll = (dot < 0.0f) && (d2 <= 0.25f);
        const unsigned long long m = __ballot(coll);
        if (lane == 0) atomicAdd(out + b, (float)__popcll(m));
    }
}

extern "C" void kernel_launch(void* const* d_in, const int* in_sizes, int n_in,
                              void* d_out, int out_size, void* d_ws, size_t ws_size,
                              hipStream_t stream) {
    const float* query   = (const float*)d_in[0];
    const float* anchor  = (const float*)d_in[1];
    const float* normals = (const float*)d_in[2];
    float* out = (float*)d_out;
    float4* packed = (float4*)d_ws;        // BATCH*NAPAD*16B = 442 KB

    const int npre = BATCH * NAPAD;
    precompute_kernel<<<dim3((npre + 255) / 256), dim3(256), 0, stream>>>(
        anchor, packed, out);

    const int grid = BATCH * 64;           // 256 blocks x 1024 threads = 1 block/CU
    collision_kernel<<<dim3(grid), dim3(NSPLIT * 64), 0, stream>>>(
        query, anchor, normals, packed, out);
}

// Round 7
// 101.569 us; speedup vs baseline: 1.5801x; 1.1720x over previous
//
#include <hip/hip_runtime.h>

// Problem constants (from reference setup_inputs).
#define BATCH 4
#define NQ    8192
#define NA    6890
#define NT    216              // anchor tiles of 32
#define NAPAD (NT*32)          // 6912
#define KS    32               // k-slots per row (two 32x32x16 MFMAs)
#define TPW   54               // a-tiles per wave (216 / 4 waves)

typedef __attribute__((ext_vector_type(8)))  short bf16x8;
typedef __attribute__((ext_vector_type(16))) float f32x16;

#define A_ROWS (BATCH*NQ)      // 32768
#define B_ROWS (BATCH*NAPAD)   // 27648
#define A_BYTES ((size_t)A_ROWS*KS*2)   // 2 MB

__device__ __forceinline__ unsigned short f2bf(float x) {   // RNE fp32->bf16
    unsigned b = __float_as_uint(x);
    b += 0x7FFFu + ((b >> 16) & 1u);
    return (unsigned short)(b >> 16);
}
__device__ __forceinline__ float bf2f(unsigned short u) {
    return __uint_as_float(((unsigned)u) << 16);
}
// 3-term bf16 split: x = h + m + l + O(2^-27 x)
__device__ __forceinline__ void split3(float x, unsigned short o[3]) {
    const unsigned short h = f2bf(x); const float fh = bf2f(h);
    const float r1 = x - fh;
    const unsigned short m = f2bf(r1); const float fm = bf2f(m);
    o[0] = h; o[1] = m; o[2] = f2bf(r1 - fm);
}

// k-slot term table: slot = d*8+p. Pair p -> (q-term, a-term), h=0 m=1 l=2.
// Kept pairs: hh,hm,mh,hl,mm,lh,ml,lm (drop ll ~ 2^-27).
__constant__ int QT_OF[8] = {0,0,1,0,1,2,1,2};
__constant__ int AT_OF[8] = {0,1,0,2,1,0,2,1};

// Build A_ext[b][q][32] (negated q terms + 1.0s + q^2/2 splits) and
// B_ext[b][a][32] (a terms + |a|^2/2 splits + 1.0s); zero d_out.
// acc = sum_k A*B = q^2/2 + |a|^2/2 - q.a = d^2/2 >= 0.
__global__ void precompute_kernel(const float* __restrict__ query,
                                  const float* __restrict__ anchor,
                                  unsigned short* __restrict__ Aext,
                                  unsigned short* __restrict__ Bext,
                                  float* __restrict__ out) {
    const int i = blockIdx.x * blockDim.x + threadIdx.x;
    if (i < BATCH) out[i] = 0.0f;              // d_out poisoned each call
    unsigned short s[KS];
    #pragma unroll
    for (int k = 0; k < KS; ++k) s[k] = 0;

    if (i < A_ROWS) {                          // one query row
        const float* qp = query + (size_t)i * 3;
        const float qx = qp[0], qy = qp[1], qz = qp[2];
        unsigned short sp[3][3];
        split3(qx, sp[0]); split3(qy, sp[1]); split3(qz, sp[2]);
        #pragma unroll
        for (int d = 0; d < 3; ++d)
            #pragma unroll
            for (int p = 0; p < 8; ++p)
                s[d*8+p] = sp[d][QT_OF[p]] ^ 0x8000;   // negate: -q terms
        s[24] = s[25] = s[26] = 0x3F80;                // 1.0 (pairs |a|^2/2)
        unsigned short q2s[3];
        split3(0.5f * (qx*qx + qy*qy + qz*qz), q2s);
        s[27] = q2s[0]; s[28] = q2s[1]; s[29] = q2s[2];
        uint4* dst = (uint4*)(Aext + (size_t)i * KS);
        const uint4* sv = (const uint4*)s;
        dst[0]=sv[0]; dst[1]=sv[1]; dst[2]=sv[2]; dst[3]=sv[3];
    } else if (i < A_ROWS + B_ROWS) {          // one anchor row
        const int j = i - A_ROWS;
        const int b = j / NAPAD, k = j - b * NAPAD;
        if (k < NA) {
            const float* ap = anchor + ((size_t)b * NA + k) * 3;
            const float ax = ap[0], ay = ap[1], az = ap[2];
            unsigned short sp[3][3];
            split3(ax, sp[0]); split3(ay, sp[1]); split3(az, sp[2]);
            #pragma unroll
            for (int d = 0; d < 3; ++d)
                #pragma unroll
                for (int p = 0; p < 8; ++p)
                    s[d*8+p] = sp[d][AT_OF[p]];
            unsigned short hs[3];
            split3(0.5f * (ax*ax + ay*ay + az*az), hs);
            s[24] = hs[0]; s[25] = hs[1]; s[26] = hs[2];
        } else {
            s[24] = f2bf(1.0e30f);             // pad: score = huge, never wins
        }
        s[27] = s[28] = s[29] = 0x3F80;        // 1.0 (pairs q^2/2)
        uint4* dst = (uint4*)(Bext + (size_t)j * KS);
        const uint4* sv = (const uint4*)s;
        dst[0]=sv[0]; dst[1]=sv[1]; dst[2]=sv[2]; dst[3]=sv[3];
    }
}

// One block = one 32-query tile; 4 waves split the 216 anchor tiles.
// 32x32x16 bf16 MFMA: A[m=lane&31][k=(lane>>5)*8+j]; B[k][n=lane&31] same k
// packing; C/D: col=lane&31, row=(reg&3)+8*(reg>>2)+4*(lane>>5)  [m74/m101].
__global__ __launch_bounds__(256, 4)
void collision_kernel(const float* __restrict__ query,
                      const float* __restrict__ anchor,
                      const float* __restrict__ normals,
                      const unsigned short* __restrict__ Aext,
                      const unsigned short* __restrict__ Bext,
                      float* __restrict__ out) {
    __shared__ unsigned s_key[4][32][32];     // [wave][col][swizzled row] 16 KB

    const int lane = threadIdx.x & 63;
    const int wave = threadIdx.x >> 6;
    const int b  = blockIdx.x >> 8;           // batch
    const int qt = blockIdx.x & 255;          // query tile (32 queries)
    const int col = lane & 31;
    const int hi  = lane >> 5;

    const unsigned short* Arow = Aext + ((size_t)b*NQ + qt*32 + col) * KS + hi*8;
    const bf16x8 af0 = *(const bf16x8*)(Arow);        // k 0..15 half
    const bf16x8 af1 = *(const bf16x8*)(Arow + 16);   // k 16..31 half

    const f32x16 zero = {0,0,0,0,0,0,0,0,0,0,0,0,0,0,0,0};
    unsigned run[16];
    #pragma unroll
    for (int r = 0; r < 16; ++r) run[r] = 0xFFFFFFFFu;

    const unsigned short* Bbase = Bext + (size_t)b*NAPAD*KS + hi*8;
    const int t0 = wave * TPW;
    #pragma unroll 2
    for (int ti = 0; ti < TPW; ++ti) {
        const int t = t0 + ti;
        const unsigned short* Brow = Bbase + (size_t)(t*32 + col) * KS;
        const bf16x8 bf0 = *(const bf16x8*)(Brow);
        const bf16x8 bf1 = *(const bf16x8*)(Brow + 16);
        f32x16 acc = __builtin_amdgcn_mfma_f32_32x32x16_bf16(af0, bf0, zero, 0,0,0);
        acc        = __builtin_amdgcn_mfma_f32_32x32x16_bf16(af1, bf1, acc,  0,0,0);
        // score=d^2/2>=0: float bits order as uint. Pack anchor idx (13 bits).
        const unsigned aidx = (unsigned)(t*32 + col);
        #pragma unroll
        for (int r = 0; r < 16; ++r) {
            const unsigned key = (__float_as_uint(acc[r]) & 0xFFFFE000u) | aidx;
            run[r] = (key < run[r]) ? key : run[r];
        }
    }

    // Transpose to LDS, swizzled so both write and read are conflict-free.
    #pragma unroll
    for (int r = 0; r < 16; ++r) {
        const int row = (r & 3) + 8*(r >> 2) + 4*hi;
        s_key[wave][col][(row + col) & 31] = run[r];
    }
    __syncthreads();

    if (threadIdx.x < 32) {
        const int t = threadIdx.x;            // query row within tile
        unsigned bk = 0xFFFFFFFFu;
        #pragma unroll
        for (int w = 0; w < 4; ++w)
            #pragma unroll
            for (int c = 0; c < 32; ++c) {
                const unsigned v = s_key[w][c][(t + c) & 31];
                bk = (v < bk) ? v : bk;
            }
        const int bidx = (int)(bk & 0x1FFFu); // < NA (pads can't win)
        const int qq = qt*32 + t;
        const float* qp = query   + ((size_t)b*NQ + qq)   * 3;
        const float* ap = anchor  + ((size_t)b*NA + bidx) * 3;
        const float* np = normals + ((size_t)b*NA + bidx) * 3;
        const float qx = qp[0], qy = qp[1], qz = qp[2];
        const float dx = qx-ap[0], dy = qy-ap[1], dz = qz-ap[2];
        const float d2  = fmaf(dz, dz, fmaf(dy, dy, dx*dx));
        const float dot = fmaf(dz, np[2], fmaf(dy, np[1], dx*np[0]));
        // dot * (l2 <= 0.5) < 0  <=>  dot < 0 && d2 <= 0.25
        const bool coll = (dot < 0.0f) && (d2 <= 0.25f);
        const unsigned long long m = __ballot(coll);
        if (t == 0) atomicAdd(out + b, (float)__popcll(m));
    }
}

extern "C" void kernel_launch(void* const* d_in, const int* in_sizes, int n_in,
                              void* d_out, int out_size, void* d_ws, size_t ws_size,
                              hipStream_t stream) {
    const float* query   = (const float*)d_in[0];
    const float* anchor  = (const float*)d_in[1];
    const float* normals = (const float*)d_in[2];
    float* out = (float*)d_out;
    unsigned short* Aext = (unsigned short*)d_ws;              // 2 MB
    unsigned short* Bext = (unsigned short*)((char*)d_ws + A_BYTES); // 1.73 MB

    const int npre = A_ROWS + B_ROWS;                          // 60416
    precompute_kernel<<<dim3((npre + 255) / 256), dim3(256), 0, stream>>>(
        query, anchor, Aext, Bext, out);

    const int grid = BATCH * 256;             // 1024 blocks x 256 threads
    collision_kernel<<<dim3(grid), dim3(256), 0, stream>>>(
        query, anchor, normals, Aext, Bext, out);
}